// Round 5
// baseline (334.090 us; speedup 1.0000x reference)
//
#include <hip/hip_runtime.h>

// GCN decoder: z2 = A( relu(A(x)@W1 + b1) )@W2 + b2,  A = D^-1/2 (Adj+I) D^-1/2
// Aggregation at width-128 both layers, CSR gather, hierarchical scan.
// Round 5: LDS-free register GEMM. All GEMM operands pre-split bf16 hi/lo planes;
// fragments loaded straight from global (L2-resident), no LDS, no barriers.

constexpr int F = 128;    // aggregation width
constexpr int HID = 256;  // hidden width

typedef __attribute__((ext_vector_type(8))) short bf16x8;
typedef __attribute__((ext_vector_type(4))) float f32x4;

__device__ inline unsigned short f2bf(float f) {
  unsigned u = __float_as_uint(f);
  u += 0x7fffu + ((u >> 16) & 1u);  // round-to-nearest-even
  return (unsigned short)(u >> 16);
}
__device__ inline float bf2f(unsigned short s) {
  return __uint_as_float(((unsigned)s) << 16);
}

__global__ __launch_bounds__(256) void k_zero_deg(unsigned* deg, int N) {
  int i = blockIdx.x * 256 + threadIdx.x;
  if (i < N) deg[i] = 0u;
}

__global__ __launch_bounds__(256) void k_deg_hist(const int* __restrict__ dst,
                                                  unsigned* deg, int E) {
  int e = blockIdx.x * 256 + threadIdx.x;
  if (e < E) atomicAdd(&deg[dst[e]], 1u);
}

__global__ __launch_bounds__(256) void k_dinv(const unsigned* __restrict__ deg,
                                              float* dinv, int N) {
  int i = blockIdx.x * 256 + threadIdx.x;
  if (i < N) dinv[i] = rsqrtf((float)deg[i] + 1.0f);  // +1 = self-loop
}

// transpose + split W[K][Nn] -> hi/lo [Nn][K] bf16
__global__ __launch_bounds__(256) void k_wsplit(const float* __restrict__ W,
                                                unsigned short* __restrict__ hi,
                                                unsigned short* __restrict__ lo,
                                                int K, int Nn) {
  int idx = blockIdx.x * 256 + threadIdx.x;
  if (idx >= K * Nn) return;
  int k = idx / Nn, n = idx - k * Nn;
  float f = W[idx];
  unsigned short h = f2bf(f);
  unsigned short l = f2bf(f - bf2f(h));
  hi[n * K + k] = h;
  lo[n * K + k] = l;
}

// scan stage 1
__global__ __launch_bounds__(256) void k_scan1(const unsigned* __restrict__ deg,
                                               int* __restrict__ rowptr,
                                               unsigned* __restrict__ bsum, int N) {
  __shared__ unsigned wsum[4];
  int i = blockIdx.x * 256 + threadIdx.x;
  unsigned v = (i < N) ? deg[i] : 0u;
  unsigned sv = v;
#pragma unroll
  for (int off = 1; off < 64; off <<= 1) {
    unsigned t = __shfl_up(sv, off);
    if ((int)(threadIdx.x & 63) >= off) sv += t;
  }
  int w = threadIdx.x >> 6;
  if ((threadIdx.x & 63) == 63) wsum[w] = sv;
  __syncthreads();
  unsigned wpre = 0;
  for (int k = 0; k < w; ++k) wpre += wsum[k];
  unsigned excl = wpre + sv - v;
  if (i < N) rowptr[i] = (int)excl;
  if (threadIdx.x == 255) bsum[blockIdx.x] = excl + v;
}

// scan stage 2
__global__ __launch_bounds__(256) void k_scan2(unsigned* __restrict__ bsum,
                                               int* __restrict__ rowptr, int nb, int N) {
  __shared__ unsigned wsum[4];
  __shared__ unsigned carry;
  if (threadIdx.x == 0) carry = 0u;
  __syncthreads();
  for (int c0 = 0; c0 < nb; c0 += 256) {
    int i = c0 + threadIdx.x;
    unsigned v = (i < nb) ? bsum[i] : 0u;
    unsigned sv = v;
#pragma unroll
    for (int off = 1; off < 64; off <<= 1) {
      unsigned t = __shfl_up(sv, off);
      if ((int)(threadIdx.x & 63) >= off) sv += t;
    }
    int w = threadIdx.x >> 6;
    if ((threadIdx.x & 63) == 63) wsum[w] = sv;
    __syncthreads();
    unsigned wpre = 0;
    for (int k = 0; k < w; ++k) wpre += wsum[k];
    unsigned excl = carry + wpre + sv - v;
    if (i < nb) bsum[i] = excl;
    __syncthreads();
    if (threadIdx.x == 255) carry = excl + v;
    __syncthreads();
  }
  if (threadIdx.x == 0) rowptr[N] = (int)carry;
}

// scan stage 3: add block offsets; zero the scatter cursor
__global__ __launch_bounds__(256) void k_scan3(const unsigned* __restrict__ bsum,
                                               int* __restrict__ rowptr,
                                               unsigned* __restrict__ cursor, int N) {
  int i = blockIdx.x * 256 + threadIdx.x;
  if (i < N) {
    rowptr[i] += (int)bsum[blockIdx.x];
    cursor[i] = 0u;
  }
}

// Bucket edges by dst
__global__ __launch_bounds__(256) void k_scatter(const int* __restrict__ src,
                                                 const int* __restrict__ dst,
                                                 const int* __restrict__ rowptr,
                                                 unsigned* __restrict__ cursor,
                                                 const float* __restrict__ dinv,
                                                 int* __restrict__ esrc,
                                                 float* __restrict__ ew, int E) {
  int e = blockIdx.x * 256 + threadIdx.x;
  if (e >= E) return;
  int s = src[e], d = dst[e];
  unsigned pos = (unsigned)rowptr[d] + atomicAdd(&cursor[d], 1u);
  esrc[pos] = s;
  ew[pos] = dinv[s] * dinv[d];
}

// One wave per node, gather fp32 rows; write split-bf16 hi/lo planes (layer 1)
__global__ __launch_bounds__(256) void k_agg_bf(const int* __restrict__ rowptr,
                                                const int* __restrict__ esrc,
                                                const float* __restrict__ ew,
                                                const float* __restrict__ dinv,
                                                const float* __restrict__ h,
                                                unsigned short* __restrict__ outh,
                                                unsigned short* __restrict__ outl,
                                                int N) {
  int node = blockIdx.x * 4 + (threadIdx.x >> 6);
  int lane = threadIdx.x & 63;
  if (node >= N) return;
  float di = dinv[node];
  float w0 = di * di;
  float2 acc = ((const float2*)(h + (size_t)node * F))[lane];
  acc.x *= w0; acc.y *= w0;
  int beg = rowptr[node], end = rowptr[node + 1];
  for (int b = beg; b < end; b += 64) {
    int n = min(64, end - b);
    int s = 0;
    float w = 0.f;
    if (lane < n) {
      s = esrc[b + lane];
      w = ew[b + lane];
    }
    int t = 0;
    for (; t + 1 < n; t += 2) {
      int s0 = __shfl(s, t), s1 = __shfl(s, t + 1);
      float wa = __shfl(w, t), wb = __shfl(w, t + 1);
      float2 v0 = ((const float2*)(h + (size_t)s0 * F))[lane];
      float2 v1 = ((const float2*)(h + (size_t)s1 * F))[lane];
      acc.x += v0.x * wa; acc.y += v0.y * wa;
      acc.x += v1.x * wb; acc.y += v1.y * wb;
    }
    if (t < n) {
      int s0 = __shfl(s, t);
      float wa = __shfl(w, t);
      float2 v0 = ((const float2*)(h + (size_t)s0 * F))[lane];
      acc.x += v0.x * wa; acc.y += v0.y * wa;
    }
  }
  unsigned short hx = f2bf(acc.x), hy = f2bf(acc.y);
  unsigned short lx = f2bf(acc.x - bf2f(hx)), ly = f2bf(acc.y - bf2f(hy));
  ushort2 hv; hv.x = hx; hv.y = hy;
  ushort2 lv; lv.x = lx; lv.y = ly;
  ((ushort2*)(outh + (size_t)node * F))[lane] = hv;
  ((ushort2*)(outl + (size_t)node * F))[lane] = lv;
}

// One wave per node, fp32 gather + bias -> fp32 out (layer 2, final)
__global__ __launch_bounds__(256) void k_agg_f32(const int* __restrict__ rowptr,
                                                 const int* __restrict__ esrc,
                                                 const float* __restrict__ ew,
                                                 const float* __restrict__ dinv,
                                                 const float* __restrict__ h,
                                                 const float* __restrict__ bias,
                                                 float* __restrict__ outp, int N) {
  int node = blockIdx.x * 4 + (threadIdx.x >> 6);
  int lane = threadIdx.x & 63;
  if (node >= N) return;
  float di = dinv[node];
  float w0 = di * di;
  float2 acc = ((const float2*)(h + (size_t)node * F))[lane];
  float2 bb = ((const float2*)bias)[lane];
  acc.x = acc.x * w0 + bb.x;
  acc.y = acc.y * w0 + bb.y;
  int beg = rowptr[node], end = rowptr[node + 1];
  for (int b = beg; b < end; b += 64) {
    int n = min(64, end - b);
    int s = 0;
    float w = 0.f;
    if (lane < n) {
      s = esrc[b + lane];
      w = ew[b + lane];
    }
    int t = 0;
    for (; t + 1 < n; t += 2) {
      int s0 = __shfl(s, t), s1 = __shfl(s, t + 1);
      float wa = __shfl(w, t), wb = __shfl(w, t + 1);
      float2 v0 = ((const float2*)(h + (size_t)s0 * F))[lane];
      float2 v1 = ((const float2*)(h + (size_t)s1 * F))[lane];
      acc.x += v0.x * wa; acc.y += v0.y * wa;
      acc.x += v1.x * wb; acc.y += v1.y * wb;
    }
    if (t < n) {
      int s0 = __shfl(s, t);
      float wa = __shfl(w, t);
      float2 v0 = ((const float2*)(h + (size_t)s0 * F))[lane];
      acc.x += v0.x * wa; acc.y += v0.y * wa;
    }
  }
  ((float2*)(outp + (size_t)node * F))[lane] = acc;
}

// LDS-free register GEMM on pre-split bf16 planes.
// C[M,Nc] = (Ah+Al)[M,K] @ (Bh+Bl)^T[Nc,K]  (3-term split, fp32 acc)
// Block 256 thr = 4 waves; wave (wr,wc) owns 32x32 of the 64x64 tile.
// Every operand fragment is 16 contiguous bytes per lane, loaded from global.
template <int K, int SPLIT_OUT, int RELU>
__global__ __launch_bounds__(256) void k_rgemm(const unsigned short* __restrict__ Ah,
                                               const unsigned short* __restrict__ Al,
                                               const unsigned short* __restrict__ Bh,
                                               const unsigned short* __restrict__ Bl,
                                               const float* __restrict__ bias,
                                               float* __restrict__ Cf,
                                               unsigned short* __restrict__ Ch,
                                               unsigned short* __restrict__ Cl,
                                               int M, int Nc) {
  int tid = threadIdx.x;
  int lane = tid & 63, wid = tid >> 6;
  int wr = wid >> 1, wc = wid & 1;
  int row0 = blockIdx.x * 64, col0 = blockIdx.y * 64;
  int koct = (lane >> 4) * 8;  // k-octet within 32-k step

  const unsigned short *pah[2], *pal[2], *pbh[2], *pbl[2];
#pragma unroll
  for (int mf = 0; mf < 2; ++mf) {
    int r = row0 + wr * 32 + mf * 16 + (lane & 15);
    if (r >= M) r = M - 1;  // clamped load, result discarded at store
    pah[mf] = Ah + (size_t)r * K + koct;
    pal[mf] = Al + (size_t)r * K + koct;
  }
#pragma unroll
  for (int nf = 0; nf < 2; ++nf) {
    int c = col0 + wc * 32 + nf * 16 + (lane & 15);
    pbh[nf] = Bh + (size_t)c * K + koct;
    pbl[nf] = Bl + (size_t)c * K + koct;
  }

  f32x4 acc[2][2] = {};
#pragma unroll 2
  for (int ks = 0; ks < K / 32; ++ks) {
    int ko = ks * 32;
    bf16x8 a_h[2], a_l[2], b_h[2], b_l[2];
#pragma unroll
    for (int mf = 0; mf < 2; ++mf) {
      a_h[mf] = *(const bf16x8*)(pah[mf] + ko);
      a_l[mf] = *(const bf16x8*)(pal[mf] + ko);
    }
#pragma unroll
    for (int nf = 0; nf < 2; ++nf) {
      b_h[nf] = *(const bf16x8*)(pbh[nf] + ko);
      b_l[nf] = *(const bf16x8*)(pbl[nf] + ko);
    }
#pragma unroll
    for (int mf = 0; mf < 2; ++mf)
#pragma unroll
      for (int nf = 0; nf < 2; ++nf) {
        acc[mf][nf] = __builtin_amdgcn_mfma_f32_16x16x32_bf16(
            a_h[mf], b_h[nf], acc[mf][nf], 0, 0, 0);
        acc[mf][nf] = __builtin_amdgcn_mfma_f32_16x16x32_bf16(
            a_h[mf], b_l[nf], acc[mf][nf], 0, 0, 0);
        acc[mf][nf] = __builtin_amdgcn_mfma_f32_16x16x32_bf16(
            a_l[mf], b_h[nf], acc[mf][nf], 0, 0, 0);
      }
  }

  // epilogue: D col=lane&15, row=(lane>>4)*4+reg
#pragma unroll
  for (int mf = 0; mf < 2; ++mf) {
    int r0 = row0 + wr * 32 + mf * 16 + (lane >> 4) * 4;
#pragma unroll
    for (int nf = 0; nf < 2; ++nf) {
      int c = col0 + wc * 32 + nf * 16 + (lane & 15);
      float bv = bias ? bias[c] : 0.f;
#pragma unroll
      for (int r = 0; r < 4; ++r) {
        if (r0 + r < M) {
          float v = acc[mf][nf][r] + bv;
          if (RELU) v = fmaxf(v, 0.f);
          if (SPLIT_OUT) {
            unsigned short hh = f2bf(v);
            Ch[(size_t)(r0 + r) * Nc + c] = hh;
            Cl[(size_t)(r0 + r) * Nc + c] = f2bf(v - bf2f(hh));
          } else {
            Cf[(size_t)(r0 + r) * Nc + c] = v;
          }
        }
      }
    }
  }
}

extern "C" void kernel_launch(void* const* d_in, const int* in_sizes, int n_in,
                              void* d_out, int out_size, void* d_ws, size_t ws_size,
                              hipStream_t stream) {
  const float* x = (const float*)d_in[0];
  const int* ei = (const int*)d_in[1];
  const float* W1 = (const float*)d_in[2];
  const float* b1 = (const float*)d_in[3];
  const float* W2 = (const float*)d_in[4];
  const float* b2 = (const float*)d_in[5];
  float* out = (float*)d_out;

  int N = in_sizes[0] / F;  // 50000
  int E = in_sizes[1] / 2;  // 800000
  const int* src = ei;
  const int* dst = ei + E;

  // workspace layout (byte-based, 256B aligned chunks)
  char* ws = (char*)d_ws;
  size_t off = 0;
  auto allocB = [&](size_t bytes) {
    void* p = ws + off;
    off += ((bytes + 255) & ~(size_t)255);
    return p;
  };
  unsigned* deg = (unsigned*)allocB((size_t)N * 4);  // histogram, then cursor
  float* dinv = (float*)allocB((size_t)N * 4);
  int* rowptr = (int*)allocB(((size_t)N + 1) * 4);
  unsigned* bsum = (unsigned*)allocB(1024);
  int* esrc = (int*)allocB((size_t)E * 4);
  float* ew = (float*)allocB((size_t)E * 4);
  unsigned short* aggh = (unsigned short*)allocB((size_t)N * F * 2);  // layer-1 agg hi
  unsigned short* aggl = (unsigned short*)allocB((size_t)N * F * 2);  // layer-1 agg lo
  unsigned short* z1h = (unsigned short*)allocB((size_t)N * HID * 2);
  unsigned short* z1l = (unsigned short*)allocB((size_t)N * HID * 2);
  unsigned short* w1th = (unsigned short*)allocB((size_t)F * HID * 2);
  unsigned short* w1tl = (unsigned short*)allocB((size_t)F * HID * 2);
  unsigned short* w2th = (unsigned short*)allocB((size_t)HID * F * 2);
  unsigned short* w2tl = (unsigned short*)allocB((size_t)HID * F * 2);
  // h2 fp32 reuses the (dead after GEMM1) agg plane region: 2 x 12.8 MB = 25.6 MB
  float* h2 = (float*)aggh;

  int nbN = (N + 255) / 256;
  int nbE = (E + 255) / 256;
  int nbW = (F * HID + 255) / 256;

  k_wsplit<<<nbW, 256, 0, stream>>>(W1, w1th, w1tl, F, HID);  // [HID][F]
  k_wsplit<<<nbW, 256, 0, stream>>>(W2, w2th, w2tl, HID, F);  // [F][HID]

  k_zero_deg<<<nbN, 256, 0, stream>>>(deg, N);
  k_deg_hist<<<nbE, 256, 0, stream>>>(dst, deg, E);
  k_dinv<<<nbN, 256, 0, stream>>>(deg, dinv, N);
  k_scan1<<<nbN, 256, 0, stream>>>(deg, rowptr, bsum, N);
  k_scan2<<<1, 256, 0, stream>>>(bsum, rowptr, nbN, N);
  k_scan3<<<nbN, 256, 0, stream>>>(bsum, rowptr, deg, N);
  k_scatter<<<nbE, 256, 0, stream>>>(src, dst, rowptr, deg, dinv, esrc, ew, E);

  int nbAgg = (N + 3) / 4;
  int mb = (N + 63) / 64;

  // layer 1: agg(hi/lo) = A x ; z1(hi/lo) = relu(agg @ W1 + b1)
  k_agg_bf<<<nbAgg, 256, 0, stream>>>(rowptr, esrc, ew, dinv, x, aggh, aggl, N);
  dim3 g1(mb, HID / 64);
  k_rgemm<128, 1, 1><<<g1, 256, 0, stream>>>(aggh, aggl, w1th, w1tl, b1,
                                             nullptr, z1h, z1l, N, HID);

  // layer 2: h2 = z1 @ W2 (fp32 out) ; out = b2 + A h2
  dim3 g2(mb, F / 64);
  k_rgemm<256, 0, 0><<<g2, 256, 0, stream>>>(z1h, z1l, w2th, w2tl, nullptr,
                                             h2, nullptr, nullptr, N, F);
  k_agg_f32<<<nbAgg, 256, 0, stream>>>(rowptr, esrc, ew, dinv, h2, b2, out, N);
}

// Round 6
// 270.565 us; speedup vs baseline: 1.2348x; 1.2348x over previous
//
#include <hip/hip_runtime.h>

// GCN decoder: z2 = A( relu(A(x)@W1 + b1) )@W2 + b2,  A = D^-1/2 (Adj+I) D^-1/2
// Aggregation at width-128 both layers, CSR gather, hierarchical scan.
// Round 6: GEMMs = 64-row x all-cols blocks, whole-K LDS stage of A (one barrier),
// XOR-swizzled ds_read_b128, B (weights) L2-resident from global.
// z1 intermediate is bf16 hi-only (GEMM2 2-term split).

constexpr int F = 128;    // aggregation width
constexpr int HID = 256;  // hidden width

typedef __attribute__((ext_vector_type(8))) short bf16x8;
typedef __attribute__((ext_vector_type(4))) float f32x4;

__device__ inline unsigned short f2bf(float f) {
  unsigned u = __float_as_uint(f);
  u += 0x7fffu + ((u >> 16) & 1u);  // round-to-nearest-even
  return (unsigned short)(u >> 16);
}
__device__ inline float bf2f(unsigned short s) {
  return __uint_as_float(((unsigned)s) << 16);
}

__global__ __launch_bounds__(256) void k_zero_deg(unsigned* deg, int N) {
  int i = blockIdx.x * 256 + threadIdx.x;
  if (i < N) deg[i] = 0u;
}

__global__ __launch_bounds__(256) void k_deg_hist(const int* __restrict__ dst,
                                                  unsigned* deg, int E) {
  int e = blockIdx.x * 256 + threadIdx.x;
  if (e < E) atomicAdd(&deg[dst[e]], 1u);
}

__global__ __launch_bounds__(256) void k_dinv(const unsigned* __restrict__ deg,
                                              float* dinv, int N) {
  int i = blockIdx.x * 256 + threadIdx.x;
  if (i < N) dinv[i] = rsqrtf((float)deg[i] + 1.0f);  // +1 = self-loop
}

// transpose + split W[K][Nn] -> hi/lo [Nn][K] bf16
__global__ __launch_bounds__(256) void k_wsplit(const float* __restrict__ W,
                                                unsigned short* __restrict__ hi,
                                                unsigned short* __restrict__ lo,
                                                int K, int Nn) {
  int idx = blockIdx.x * 256 + threadIdx.x;
  if (idx >= K * Nn) return;
  int k = idx / Nn, n = idx - k * Nn;
  float f = W[idx];
  unsigned short h = f2bf(f);
  unsigned short l = f2bf(f - bf2f(h));
  hi[n * K + k] = h;
  lo[n * K + k] = l;
}

// scan stage 1
__global__ __launch_bounds__(256) void k_scan1(const unsigned* __restrict__ deg,
                                               int* __restrict__ rowptr,
                                               unsigned* __restrict__ bsum, int N) {
  __shared__ unsigned wsum[4];
  int i = blockIdx.x * 256 + threadIdx.x;
  unsigned v = (i < N) ? deg[i] : 0u;
  unsigned sv = v;
#pragma unroll
  for (int off = 1; off < 64; off <<= 1) {
    unsigned t = __shfl_up(sv, off);
    if ((int)(threadIdx.x & 63) >= off) sv += t;
  }
  int w = threadIdx.x >> 6;
  if ((threadIdx.x & 63) == 63) wsum[w] = sv;
  __syncthreads();
  unsigned wpre = 0;
  for (int k = 0; k < w; ++k) wpre += wsum[k];
  unsigned excl = wpre + sv - v;
  if (i < N) rowptr[i] = (int)excl;
  if (threadIdx.x == 255) bsum[blockIdx.x] = excl + v;
}

// scan stage 2
__global__ __launch_bounds__(256) void k_scan2(unsigned* __restrict__ bsum,
                                               int* __restrict__ rowptr, int nb, int N) {
  __shared__ unsigned wsum[4];
  __shared__ unsigned carry;
  if (threadIdx.x == 0) carry = 0u;
  __syncthreads();
  for (int c0 = 0; c0 < nb; c0 += 256) {
    int i = c0 + threadIdx.x;
    unsigned v = (i < nb) ? bsum[i] : 0u;
    unsigned sv = v;
#pragma unroll
    for (int off = 1; off < 64; off <<= 1) {
      unsigned t = __shfl_up(sv, off);
      if ((int)(threadIdx.x & 63) >= off) sv += t;
    }
    int w = threadIdx.x >> 6;
    if ((threadIdx.x & 63) == 63) wsum[w] = sv;
    __syncthreads();
    unsigned wpre = 0;
    for (int k = 0; k < w; ++k) wpre += wsum[k];
    unsigned excl = carry + wpre + sv - v;
    if (i < nb) bsum[i] = excl;
    __syncthreads();
    if (threadIdx.x == 255) carry = excl + v;
    __syncthreads();
  }
  if (threadIdx.x == 0) rowptr[N] = (int)carry;
}

// scan stage 3: add block offsets; zero the scatter cursor
__global__ __launch_bounds__(256) void k_scan3(const unsigned* __restrict__ bsum,
                                               int* __restrict__ rowptr,
                                               unsigned* __restrict__ cursor, int N) {
  int i = blockIdx.x * 256 + threadIdx.x;
  if (i < N) {
    rowptr[i] += (int)bsum[blockIdx.x];
    cursor[i] = 0u;
  }
}

// Bucket edges by dst
__global__ __launch_bounds__(256) void k_scatter(const int* __restrict__ src,
                                                 const int* __restrict__ dst,
                                                 const int* __restrict__ rowptr,
                                                 unsigned* __restrict__ cursor,
                                                 const float* __restrict__ dinv,
                                                 int* __restrict__ esrc,
                                                 float* __restrict__ ew, int E) {
  int e = blockIdx.x * 256 + threadIdx.x;
  if (e >= E) return;
  int s = src[e], d = dst[e];
  unsigned pos = (unsigned)rowptr[d] + atomicAdd(&cursor[d], 1u);
  esrc[pos] = s;
  ew[pos] = dinv[s] * dinv[d];
}

// One wave per node, gather fp32 rows; write split-bf16 hi/lo planes (layer-1 agg)
__global__ __launch_bounds__(256) void k_agg_bf(const int* __restrict__ rowptr,
                                                const int* __restrict__ esrc,
                                                const float* __restrict__ ew,
                                                const float* __restrict__ dinv,
                                                const float* __restrict__ h,
                                                unsigned short* __restrict__ outh,
                                                unsigned short* __restrict__ outl,
                                                int N) {
  int node = blockIdx.x * 4 + (threadIdx.x >> 6);
  int lane = threadIdx.x & 63;
  if (node >= N) return;
  float di = dinv[node];
  float w0 = di * di;
  float2 acc = ((const float2*)(h + (size_t)node * F))[lane];
  acc.x *= w0; acc.y *= w0;
  int beg = rowptr[node], end = rowptr[node + 1];
  for (int b = beg; b < end; b += 64) {
    int n = min(64, end - b);
    int s = 0;
    float w = 0.f;
    if (lane < n) {
      s = esrc[b + lane];
      w = ew[b + lane];
    }
    int t = 0;
    for (; t + 1 < n; t += 2) {
      int s0 = __shfl(s, t), s1 = __shfl(s, t + 1);
      float wa = __shfl(w, t), wb = __shfl(w, t + 1);
      float2 v0 = ((const float2*)(h + (size_t)s0 * F))[lane];
      float2 v1 = ((const float2*)(h + (size_t)s1 * F))[lane];
      acc.x += v0.x * wa; acc.y += v0.y * wa;
      acc.x += v1.x * wb; acc.y += v1.y * wb;
    }
    if (t < n) {
      int s0 = __shfl(s, t);
      float wa = __shfl(w, t);
      float2 v0 = ((const float2*)(h + (size_t)s0 * F))[lane];
      acc.x += v0.x * wa; acc.y += v0.y * wa;
    }
  }
  unsigned short hx = f2bf(acc.x), hy = f2bf(acc.y);
  unsigned short lx = f2bf(acc.x - bf2f(hx)), ly = f2bf(acc.y - bf2f(hy));
  ushort2 hv; hv.x = hx; hv.y = hy;
  ushort2 lv; lv.x = lx; lv.y = ly;
  ((ushort2*)(outh + (size_t)node * F))[lane] = hv;
  ((ushort2*)(outl + (size_t)node * F))[lane] = lv;
}

// One wave per node, fp32 gather + bias -> fp32 out (layer 2, final)
__global__ __launch_bounds__(256) void k_agg_f32(const int* __restrict__ rowptr,
                                                 const int* __restrict__ esrc,
                                                 const float* __restrict__ ew,
                                                 const float* __restrict__ dinv,
                                                 const float* __restrict__ h,
                                                 const float* __restrict__ bias,
                                                 float* __restrict__ outp, int N) {
  int node = blockIdx.x * 4 + (threadIdx.x >> 6);
  int lane = threadIdx.x & 63;
  if (node >= N) return;
  float di = dinv[node];
  float w0 = di * di;
  float2 acc = ((const float2*)(h + (size_t)node * F))[lane];
  float2 bb = ((const float2*)bias)[lane];
  acc.x = acc.x * w0 + bb.x;
  acc.y = acc.y * w0 + bb.y;
  int beg = rowptr[node], end = rowptr[node + 1];
  for (int b = beg; b < end; b += 64) {
    int n = min(64, end - b);
    int s = 0;
    float w = 0.f;
    if (lane < n) {
      s = esrc[b + lane];
      w = ew[b + lane];
    }
    int t = 0;
    for (; t + 1 < n; t += 2) {
      int s0 = __shfl(s, t), s1 = __shfl(s, t + 1);
      float wa = __shfl(w, t), wb = __shfl(w, t + 1);
      float2 v0 = ((const float2*)(h + (size_t)s0 * F))[lane];
      float2 v1 = ((const float2*)(h + (size_t)s1 * F))[lane];
      acc.x += v0.x * wa; acc.y += v0.y * wa;
      acc.x += v1.x * wb; acc.y += v1.y * wb;
    }
    if (t < n) {
      int s0 = __shfl(s, t);
      float wa = __shfl(w, t);
      float2 v0 = ((const float2*)(h + (size_t)s0 * F))[lane];
      acc.x += v0.x * wa; acc.y += v0.y * wa;
    }
  }
  ((float2*)(outp + (size_t)node * F))[lane] = acc;
}

// GEMM1: z1(bf16) = relu( (Ah+Al)[M,128] @ (W1h+W1l)^T[256,128] + b1 )
// Block: 64 rows x 256 cols, 4 waves (64 cols each). Whole K=128 of A in LDS
// (hi+lo, 32KB, XOR-swizzled), single barrier. B direct from global (L2-hot).
__global__ __launch_bounds__(256) void k_gemm1(const unsigned short* __restrict__ Ah,
                                               const unsigned short* __restrict__ Al,
                                               const unsigned short* __restrict__ Bh,
                                               const unsigned short* __restrict__ Bl,
                                               const float* __restrict__ bias,
                                               unsigned short* __restrict__ Cbf,
                                               int M) {
  __shared__ unsigned short AhL[64 * 128];
  __shared__ unsigned short AlL[64 * 128];
  int tid = threadIdx.x;
  int lane = tid & 63, wid = tid >> 6;
  int row0 = blockIdx.x * 64;

  // stage A hi+lo: 1024 granules (16B) per plane, 4 per thread, swizzled ds_write
#pragma unroll
  for (int i = 0; i < 4; ++i) {
    int g = i * 256 + tid;
    int r = g >> 4, gi = g & 15;
    int o = r * 128 + (gi ^ (r & 7)) * 8;
    size_t go = (size_t)(row0 + r) * 128 + gi * 8;
    *(bf16x8*)&AhL[o] = *(const bf16x8*)&Ah[go];
    *(bf16x8*)&AlL[o] = *(const bf16x8*)&Al[go];
  }
  __syncthreads();

  f32x4 acc[4][4] = {};
#pragma unroll
  for (int ks = 0; ks < 4; ++ks) {
    bf16x8 ah[4], al[4], bh[4], bl[4];
#pragma unroll
    for (int mf = 0; mf < 4; ++mf) {
      int r = mf * 16 + (lane & 15);
      int g = ks * 4 + (lane >> 4);
      int o = r * 128 + (g ^ (r & 7)) * 8;
      ah[mf] = *(const bf16x8*)&AhL[o];
      al[mf] = *(const bf16x8*)&AlL[o];
    }
#pragma unroll
    for (int nf = 0; nf < 4; ++nf) {
      int c = wid * 64 + nf * 16 + (lane & 15);
      size_t o = (size_t)c * 128 + ks * 32 + (lane >> 4) * 8;
      bh[nf] = *(const bf16x8*)&Bh[o];
      bl[nf] = *(const bf16x8*)&Bl[o];
    }
#pragma unroll
    for (int mf = 0; mf < 4; ++mf)
#pragma unroll
      for (int nf = 0; nf < 4; ++nf) {
        acc[mf][nf] = __builtin_amdgcn_mfma_f32_16x16x32_bf16(
            ah[mf], bh[nf], acc[mf][nf], 0, 0, 0);
        acc[mf][nf] = __builtin_amdgcn_mfma_f32_16x16x32_bf16(
            ah[mf], bl[nf], acc[mf][nf], 0, 0, 0);
        acc[mf][nf] = __builtin_amdgcn_mfma_f32_16x16x32_bf16(
            al[mf], bh[nf], acc[mf][nf], 0, 0, 0);
      }
  }

  // epilogue: D col=lane&15, row=(lane>>4)*4+reg ; z1 bf16 hi-only
#pragma unroll
  for (int mf = 0; mf < 4; ++mf) {
    int r0 = row0 + mf * 16 + (lane >> 4) * 4;
#pragma unroll
    for (int nf = 0; nf < 4; ++nf) {
      int c = wid * 64 + nf * 16 + (lane & 15);
      float bv = bias[c];
#pragma unroll
      for (int r = 0; r < 4; ++r) {
        if (r0 + r < M) {
          float v = fmaxf(acc[mf][nf][r] + bv, 0.f);
          Cbf[(size_t)(r0 + r) * HID + c] = f2bf(v);
        }
      }
    }
  }
}

// GEMM2: h2(fp32) = Z(bf16)[M,256] @ (W2h+W2l)^T[128,256]   (2-term split)
// Block: 64 rows x 128 cols, 4 waves (32 cols each). Whole K=256 of Z in LDS (32KB).
__global__ __launch_bounds__(256) void k_gemm2(const unsigned short* __restrict__ Z,
                                               const unsigned short* __restrict__ Bh,
                                               const unsigned short* __restrict__ Bl,
                                               float* __restrict__ C, int M) {
  __shared__ unsigned short ZL[64 * 256];
  int tid = threadIdx.x;
  int lane = tid & 63, wid = tid >> 6;
  int row0 = blockIdx.x * 64;

  // stage Z: 2048 granules, 8 per thread, swizzled
#pragma unroll
  for (int i = 0; i < 8; ++i) {
    int g = i * 256 + tid;
    int r = g >> 5, gi = g & 31;
    int o = r * 256 + (gi ^ (r & 7)) * 8;
    size_t go = (size_t)(row0 + r) * 256 + gi * 8;
    *(bf16x8*)&ZL[o] = *(const bf16x8*)&Z[go];
  }
  __syncthreads();

  f32x4 acc[4][2] = {};
#pragma unroll
  for (int ks = 0; ks < 8; ++ks) {
    bf16x8 ah[4], bh[2], bl[2];
#pragma unroll
    for (int mf = 0; mf < 4; ++mf) {
      int r = mf * 16 + (lane & 15);
      int g = ks * 4 + (lane >> 4);
      int o = r * 256 + (g ^ (r & 7)) * 8;
      ah[mf] = *(const bf16x8*)&ZL[o];
    }
#pragma unroll
    for (int nf = 0; nf < 2; ++nf) {
      int c = wid * 32 + nf * 16 + (lane & 15);
      size_t o = (size_t)c * 256 + ks * 32 + (lane >> 4) * 8;
      bh[nf] = *(const bf16x8*)&Bh[o];
      bl[nf] = *(const bf16x8*)&Bl[o];
    }
#pragma unroll
    for (int mf = 0; mf < 4; ++mf)
#pragma unroll
      for (int nf = 0; nf < 2; ++nf) {
        acc[mf][nf] = __builtin_amdgcn_mfma_f32_16x16x32_bf16(
            ah[mf], bh[nf], acc[mf][nf], 0, 0, 0);
        acc[mf][nf] = __builtin_amdgcn_mfma_f32_16x16x32_bf16(
            ah[mf], bl[nf], acc[mf][nf], 0, 0, 0);
      }
  }

#pragma unroll
  for (int mf = 0; mf < 4; ++mf) {
    int r0 = row0 + mf * 16 + (lane >> 4) * 4;
#pragma unroll
    for (int nf = 0; nf < 2; ++nf) {
      int c = wid * 32 + nf * 16 + (lane & 15);
#pragma unroll
      for (int r = 0; r < 4; ++r)
        if (r0 + r < M) C[(size_t)(r0 + r) * F + c] = acc[mf][nf][r];
    }
  }
}

extern "C" void kernel_launch(void* const* d_in, const int* in_sizes, int n_in,
                              void* d_out, int out_size, void* d_ws, size_t ws_size,
                              hipStream_t stream) {
  const float* x = (const float*)d_in[0];
  const int* ei = (const int*)d_in[1];
  const float* W1 = (const float*)d_in[2];
  const float* b1 = (const float*)d_in[3];
  const float* W2 = (const float*)d_in[4];
  const float* b2 = (const float*)d_in[5];
  float* out = (float*)d_out;

  int N = in_sizes[0] / F;  // 50000
  int E = in_sizes[1] / 2;  // 800000
  const int* src = ei;
  const int* dst = ei + E;

  // workspace layout (byte-based, 256B aligned chunks)
  char* ws = (char*)d_ws;
  size_t off = 0;
  auto allocB = [&](size_t bytes) {
    void* p = ws + off;
    off += ((bytes + 255) & ~(size_t)255);
    return p;
  };
  unsigned* deg = (unsigned*)allocB((size_t)N * 4);  // histogram, then cursor
  float* dinv = (float*)allocB((size_t)N * 4);
  int* rowptr = (int*)allocB(((size_t)N + 1) * 4);
  unsigned* bsum = (unsigned*)allocB(1024);
  int* esrc = (int*)allocB((size_t)E * 4);
  float* ew = (float*)allocB((size_t)E * 4);
  // +64 row padding so tail-block LDS staging reads stay in-bounds
  unsigned short* aggh = (unsigned short*)allocB((size_t)(N + 64) * F * 2);
  unsigned short* aggl = (unsigned short*)allocB((size_t)(N + 64) * F * 2);
  unsigned short* z1h = (unsigned short*)allocB((size_t)(N + 64) * HID * 2);
  unsigned short* w1th = (unsigned short*)allocB((size_t)F * HID * 2);
  unsigned short* w1tl = (unsigned short*)allocB((size_t)F * HID * 2);
  unsigned short* w2th = (unsigned short*)allocB((size_t)HID * F * 2);
  unsigned short* w2tl = (unsigned short*)allocB((size_t)HID * F * 2);
  // h2 fp32 (25.6MB) reuses the agg planes region (dead after GEMM1)
  float* h2 = (float*)aggh;

  int nbN = (N + 255) / 256;
  int nbE = (E + 255) / 256;
  int nbW = (F * HID + 255) / 256;

  k_wsplit<<<nbW, 256, 0, stream>>>(W1, w1th, w1tl, F, HID);  // [256][128]
  k_wsplit<<<nbW, 256, 0, stream>>>(W2, w2th, w2tl, HID, F);  // [128][256]

  k_zero_deg<<<nbN, 256, 0, stream>>>(deg, N);
  k_deg_hist<<<nbE, 256, 0, stream>>>(dst, deg, E);
  k_dinv<<<nbN, 256, 0, stream>>>(deg, dinv, N);
  k_scan1<<<nbN, 256, 0, stream>>>(deg, rowptr, bsum, N);
  k_scan2<<<1, 256, 0, stream>>>(bsum, rowptr, nbN, N);
  k_scan3<<<nbN, 256, 0, stream>>>(bsum, rowptr, deg, N);
  k_scatter<<<nbE, 256, 0, stream>>>(src, dst, rowptr, deg, dinv, esrc, ew, E);

  int nbAgg = (N + 3) / 4;
  int mb = (N + 63) / 64;

  // layer 1: agg(hi/lo) = A x ; z1(bf16) = relu(agg @ W1 + b1)
  k_agg_bf<<<nbAgg, 256, 0, stream>>>(rowptr, esrc, ew, dinv, x, aggh, aggl, N);
  k_gemm1<<<mb, 256, 0, stream>>>(aggh, aggl, w1th, w1tl, b1, z1h, N);

  // layer 2: h2 = z1 @ W2 ; out = b2 + A h2
  k_gemm2<<<mb, 256, 0, stream>>>(z1h, w2th, w2tl, h2, N);
  k_agg_f32<<<nbAgg, 256, 0, stream>>>(rowptr, esrc, ew, dinv, h2, b2, out, N);
}

// Round 7
// 230.408 us; speedup vs baseline: 1.4500x; 1.1743x over previous
//
#include <hip/hip_runtime.h>

// GCN decoder: z2 = A( relu(A(x)@W1 + b1) )@W2 + b2,  A = D^-1/2 (Adj+I) D^-1/2
// Aggregation at width-128 both layers, CSR gather, hierarchical scan.
// Round 7: gathers read bf16 rows (half bytes): x pre-converted to bf16 plane,
// h2 written as bf16 by GEMM2. Accumulators stay fp32; self-term of layer 1 fp32.

constexpr int F = 128;    // aggregation width
constexpr int HID = 256;  // hidden width

typedef __attribute__((ext_vector_type(8))) short bf16x8;
typedef __attribute__((ext_vector_type(4))) float f32x4;

__device__ inline unsigned short f2bf(float f) {
  unsigned u = __float_as_uint(f);
  u += 0x7fffu + ((u >> 16) & 1u);  // round-to-nearest-even
  return (unsigned short)(u >> 16);
}
__device__ inline float bf2f(unsigned short s) {
  return __uint_as_float(((unsigned)s) << 16);
}

__global__ __launch_bounds__(256) void k_zero_deg(unsigned* deg, int N) {
  int i = blockIdx.x * 256 + threadIdx.x;
  if (i < N) deg[i] = 0u;
}

__global__ __launch_bounds__(256) void k_deg_hist(const int* __restrict__ dst,
                                                  unsigned* deg, int E) {
  int e = blockIdx.x * 256 + threadIdx.x;
  if (e < E) atomicAdd(&deg[dst[e]], 1u);
}

__global__ __launch_bounds__(256) void k_dinv(const unsigned* __restrict__ deg,
                                              float* dinv, int N) {
  int i = blockIdx.x * 256 + threadIdx.x;
  if (i < N) dinv[i] = rsqrtf((float)deg[i] + 1.0f);  // +1 = self-loop
}

// fp32 -> bf16 plane (x table for layer-1 gather)
__global__ __launch_bounds__(256) void k_tobf(const float* __restrict__ in,
                                              unsigned short* __restrict__ outp,
                                              int n4) {
  int i = blockIdx.x * 256 + threadIdx.x;
  if (i >= n4) return;
  float4 v = ((const float4*)in)[i];
  ushort4 o;
  o.x = f2bf(v.x); o.y = f2bf(v.y); o.z = f2bf(v.z); o.w = f2bf(v.w);
  ((ushort4*)outp)[i] = o;
}

// transpose + split W[K][Nn] -> hi/lo [Nn][K] bf16
__global__ __launch_bounds__(256) void k_wsplit(const float* __restrict__ W,
                                                unsigned short* __restrict__ hi,
                                                unsigned short* __restrict__ lo,
                                                int K, int Nn) {
  int idx = blockIdx.x * 256 + threadIdx.x;
  if (idx >= K * Nn) return;
  int k = idx / Nn, n = idx - k * Nn;
  float f = W[idx];
  unsigned short h = f2bf(f);
  unsigned short l = f2bf(f - bf2f(h));
  hi[n * K + k] = h;
  lo[n * K + k] = l;
}

// scan stage 1
__global__ __launch_bounds__(256) void k_scan1(const unsigned* __restrict__ deg,
                                               int* __restrict__ rowptr,
                                               unsigned* __restrict__ bsum, int N) {
  __shared__ unsigned wsum[4];
  int i = blockIdx.x * 256 + threadIdx.x;
  unsigned v = (i < N) ? deg[i] : 0u;
  unsigned sv = v;
#pragma unroll
  for (int off = 1; off < 64; off <<= 1) {
    unsigned t = __shfl_up(sv, off);
    if ((int)(threadIdx.x & 63) >= off) sv += t;
  }
  int w = threadIdx.x >> 6;
  if ((threadIdx.x & 63) == 63) wsum[w] = sv;
  __syncthreads();
  unsigned wpre = 0;
  for (int k = 0; k < w; ++k) wpre += wsum[k];
  unsigned excl = wpre + sv - v;
  if (i < N) rowptr[i] = (int)excl;
  if (threadIdx.x == 255) bsum[blockIdx.x] = excl + v;
}

// scan stage 2
__global__ __launch_bounds__(256) void k_scan2(unsigned* __restrict__ bsum,
                                               int* __restrict__ rowptr, int nb, int N) {
  __shared__ unsigned wsum[4];
  __shared__ unsigned carry;
  if (threadIdx.x == 0) carry = 0u;
  __syncthreads();
  for (int c0 = 0; c0 < nb; c0 += 256) {
    int i = c0 + threadIdx.x;
    unsigned v = (i < nb) ? bsum[i] : 0u;
    unsigned sv = v;
#pragma unroll
    for (int off = 1; off < 64; off <<= 1) {
      unsigned t = __shfl_up(sv, off);
      if ((int)(threadIdx.x & 63) >= off) sv += t;
    }
    int w = threadIdx.x >> 6;
    if ((threadIdx.x & 63) == 63) wsum[w] = sv;
    __syncthreads();
    unsigned wpre = 0;
    for (int k = 0; k < w; ++k) wpre += wsum[k];
    unsigned excl = carry + wpre + sv - v;
    if (i < nb) bsum[i] = excl;
    __syncthreads();
    if (threadIdx.x == 255) carry = excl + v;
    __syncthreads();
  }
  if (threadIdx.x == 0) rowptr[N] = (int)carry;
}

// scan stage 3: add block offsets; zero the scatter cursor
__global__ __launch_bounds__(256) void k_scan3(const unsigned* __restrict__ bsum,
                                               int* __restrict__ rowptr,
                                               unsigned* __restrict__ cursor, int N) {
  int i = blockIdx.x * 256 + threadIdx.x;
  if (i < N) {
    rowptr[i] += (int)bsum[blockIdx.x];
    cursor[i] = 0u;
  }
}

// Bucket edges by dst
__global__ __launch_bounds__(256) void k_scatter(const int* __restrict__ src,
                                                 const int* __restrict__ dst,
                                                 const int* __restrict__ rowptr,
                                                 unsigned* __restrict__ cursor,
                                                 const float* __restrict__ dinv,
                                                 int* __restrict__ esrc,
                                                 float* __restrict__ ew, int E) {
  int e = blockIdx.x * 256 + threadIdx.x;
  if (e >= E) return;
  int s = src[e], d = dst[e];
  unsigned pos = (unsigned)rowptr[d] + atomicAdd(&cursor[d], 1u);
  esrc[pos] = s;
  ew[pos] = dinv[s] * dinv[d];
}

// Layer-1 agg: gather bf16 x rows, self-term fp32, write split hi/lo planes.
__global__ __launch_bounds__(256) void k_agg_bf(const int* __restrict__ rowptr,
                                                const int* __restrict__ esrc,
                                                const float* __restrict__ ew,
                                                const float* __restrict__ dinv,
                                                const float* __restrict__ xf,
                                                const unsigned short* __restrict__ xb,
                                                unsigned short* __restrict__ outh,
                                                unsigned short* __restrict__ outl,
                                                int N) {
  int node = blockIdx.x * 4 + (threadIdx.x >> 6);
  int lane = threadIdx.x & 63;
  if (node >= N) return;
  float di = dinv[node];
  float w0 = di * di;
  float2 acc = ((const float2*)(xf + (size_t)node * F))[lane];
  acc.x *= w0; acc.y *= w0;
  int beg = rowptr[node], end = rowptr[node + 1];
  for (int b = beg; b < end; b += 64) {
    int n = min(64, end - b);
    int s = 0;
    float w = 0.f;
    if (lane < n) {
      s = esrc[b + lane];
      w = ew[b + lane];
    }
    int t = 0;
    for (; t + 3 < n; t += 4) {
      int s0 = __shfl(s, t), s1 = __shfl(s, t + 1);
      int s2 = __shfl(s, t + 2), s3 = __shfl(s, t + 3);
      float wa = __shfl(w, t), wb = __shfl(w, t + 1);
      float wc = __shfl(w, t + 2), wd = __shfl(w, t + 3);
      ushort2 v0 = ((const ushort2*)(xb + (size_t)s0 * F))[lane];
      ushort2 v1 = ((const ushort2*)(xb + (size_t)s1 * F))[lane];
      ushort2 v2 = ((const ushort2*)(xb + (size_t)s2 * F))[lane];
      ushort2 v3 = ((const ushort2*)(xb + (size_t)s3 * F))[lane];
      acc.x += bf2f(v0.x) * wa; acc.y += bf2f(v0.y) * wa;
      acc.x += bf2f(v1.x) * wb; acc.y += bf2f(v1.y) * wb;
      acc.x += bf2f(v2.x) * wc; acc.y += bf2f(v2.y) * wc;
      acc.x += bf2f(v3.x) * wd; acc.y += bf2f(v3.y) * wd;
    }
    for (; t < n; ++t) {
      int s0 = __shfl(s, t);
      float wa = __shfl(w, t);
      ushort2 v0 = ((const ushort2*)(xb + (size_t)s0 * F))[lane];
      acc.x += bf2f(v0.x) * wa; acc.y += bf2f(v0.y) * wa;
    }
  }
  unsigned short hx = f2bf(acc.x), hy = f2bf(acc.y);
  unsigned short lx = f2bf(acc.x - bf2f(hx)), ly = f2bf(acc.y - bf2f(hy));
  ushort2 hv; hv.x = hx; hv.y = hy;
  ushort2 lv; lv.x = lx; lv.y = ly;
  ((ushort2*)(outh + (size_t)node * F))[lane] = hv;
  ((ushort2*)(outl + (size_t)node * F))[lane] = lv;
}

// Layer-2 agg: gather bf16 h2 rows (+self bf16) + bias -> fp32 out (final)
__global__ __launch_bounds__(256) void k_agg_out(const int* __restrict__ rowptr,
                                                 const int* __restrict__ esrc,
                                                 const float* __restrict__ ew,
                                                 const float* __restrict__ dinv,
                                                 const unsigned short* __restrict__ hb,
                                                 const float* __restrict__ bias,
                                                 float* __restrict__ outp, int N) {
  int node = blockIdx.x * 4 + (threadIdx.x >> 6);
  int lane = threadIdx.x & 63;
  if (node >= N) return;
  float di = dinv[node];
  float w0 = di * di;
  ushort2 sv2 = ((const ushort2*)(hb + (size_t)node * F))[lane];
  float2 bb = ((const float2*)bias)[lane];
  float2 acc;
  acc.x = bf2f(sv2.x) * w0 + bb.x;
  acc.y = bf2f(sv2.y) * w0 + bb.y;
  int beg = rowptr[node], end = rowptr[node + 1];
  for (int b = beg; b < end; b += 64) {
    int n = min(64, end - b);
    int s = 0;
    float w = 0.f;
    if (lane < n) {
      s = esrc[b + lane];
      w = ew[b + lane];
    }
    int t = 0;
    for (; t + 3 < n; t += 4) {
      int s0 = __shfl(s, t), s1 = __shfl(s, t + 1);
      int s2 = __shfl(s, t + 2), s3 = __shfl(s, t + 3);
      float wa = __shfl(w, t), wb = __shfl(w, t + 1);
      float wc = __shfl(w, t + 2), wd = __shfl(w, t + 3);
      ushort2 v0 = ((const ushort2*)(hb + (size_t)s0 * F))[lane];
      ushort2 v1 = ((const ushort2*)(hb + (size_t)s1 * F))[lane];
      ushort2 v2 = ((const ushort2*)(hb + (size_t)s2 * F))[lane];
      ushort2 v3 = ((const ushort2*)(hb + (size_t)s3 * F))[lane];
      acc.x += bf2f(v0.x) * wa; acc.y += bf2f(v0.y) * wa;
      acc.x += bf2f(v1.x) * wb; acc.y += bf2f(v1.y) * wb;
      acc.x += bf2f(v2.x) * wc; acc.y += bf2f(v2.y) * wc;
      acc.x += bf2f(v3.x) * wd; acc.y += bf2f(v3.y) * wd;
    }
    for (; t < n; ++t) {
      int s0 = __shfl(s, t);
      float wa = __shfl(w, t);
      ushort2 v0 = ((const ushort2*)(hb + (size_t)s0 * F))[lane];
      acc.x += bf2f(v0.x) * wa; acc.y += bf2f(v0.y) * wa;
    }
  }
  ((float2*)(outp + (size_t)node * F))[lane] = acc;
}

// GEMM1: z1(bf16) = relu( (Ah+Al)[M,128] @ (W1h+W1l)^T[256,128] + b1 )
__global__ __launch_bounds__(256) void k_gemm1(const unsigned short* __restrict__ Ah,
                                               const unsigned short* __restrict__ Al,
                                               const unsigned short* __restrict__ Bh,
                                               const unsigned short* __restrict__ Bl,
                                               const float* __restrict__ bias,
                                               unsigned short* __restrict__ Cbf,
                                               int M) {
  __shared__ unsigned short AhL[64 * 128];
  __shared__ unsigned short AlL[64 * 128];
  int tid = threadIdx.x;
  int lane = tid & 63, wid = tid >> 6;
  int row0 = blockIdx.x * 64;

#pragma unroll
  for (int i = 0; i < 4; ++i) {
    int g = i * 256 + tid;
    int r = g >> 4, gi = g & 15;
    int o = r * 128 + (gi ^ (r & 7)) * 8;
    size_t go = (size_t)(row0 + r) * 128 + gi * 8;
    *(bf16x8*)&AhL[o] = *(const bf16x8*)&Ah[go];
    *(bf16x8*)&AlL[o] = *(const bf16x8*)&Al[go];
  }
  __syncthreads();

  f32x4 acc[4][4] = {};
#pragma unroll
  for (int ks = 0; ks < 4; ++ks) {
    bf16x8 ah[4], al[4], bh[4], bl[4];
#pragma unroll
    for (int mf = 0; mf < 4; ++mf) {
      int r = mf * 16 + (lane & 15);
      int g = ks * 4 + (lane >> 4);
      int o = r * 128 + (g ^ (r & 7)) * 8;
      ah[mf] = *(const bf16x8*)&AhL[o];
      al[mf] = *(const bf16x8*)&AlL[o];
    }
#pragma unroll
    for (int nf = 0; nf < 4; ++nf) {
      int c = wid * 64 + nf * 16 + (lane & 15);
      size_t o = (size_t)c * 128 + ks * 32 + (lane >> 4) * 8;
      bh[nf] = *(const bf16x8*)&Bh[o];
      bl[nf] = *(const bf16x8*)&Bl[o];
    }
#pragma unroll
    for (int mf = 0; mf < 4; ++mf)
#pragma unroll
      for (int nf = 0; nf < 4; ++nf) {
        acc[mf][nf] = __builtin_amdgcn_mfma_f32_16x16x32_bf16(
            ah[mf], bh[nf], acc[mf][nf], 0, 0, 0);
        acc[mf][nf] = __builtin_amdgcn_mfma_f32_16x16x32_bf16(
            ah[mf], bl[nf], acc[mf][nf], 0, 0, 0);
        acc[mf][nf] = __builtin_amdgcn_mfma_f32_16x16x32_bf16(
            al[mf], bh[nf], acc[mf][nf], 0, 0, 0);
      }
  }

#pragma unroll
  for (int mf = 0; mf < 4; ++mf) {
    int r0 = row0 + mf * 16 + (lane >> 4) * 4;
#pragma unroll
    for (int nf = 0; nf < 4; ++nf) {
      int c = wid * 64 + nf * 16 + (lane & 15);
      float bv = bias[c];
#pragma unroll
      for (int r = 0; r < 4; ++r) {
        if (r0 + r < M) {
          float v = fmaxf(acc[mf][nf][r] + bv, 0.f);
          Cbf[(size_t)(r0 + r) * HID + c] = f2bf(v);
        }
      }
    }
  }
}

// GEMM2: h2(bf16) = Z(bf16)[M,256] @ (W2h+W2l)^T[128,256]   (2-term split)
__global__ __launch_bounds__(256) void k_gemm2(const unsigned short* __restrict__ Z,
                                               const unsigned short* __restrict__ Bh,
                                               const unsigned short* __restrict__ Bl,
                                               unsigned short* __restrict__ Cbf,
                                               int M) {
  __shared__ unsigned short ZL[64 * 256];
  int tid = threadIdx.x;
  int lane = tid & 63, wid = tid >> 6;
  int row0 = blockIdx.x * 64;

#pragma unroll
  for (int i = 0; i < 8; ++i) {
    int g = i * 256 + tid;
    int r = g >> 5, gi = g & 31;
    int o = r * 256 + (gi ^ (r & 7)) * 8;
    size_t go = (size_t)(row0 + r) * 256 + gi * 8;
    *(bf16x8*)&ZL[o] = *(const bf16x8*)&Z[go];
  }
  __syncthreads();

  f32x4 acc[4][2] = {};
#pragma unroll
  for (int ks = 0; ks < 8; ++ks) {
    bf16x8 ah[4], bh[2], bl[2];
#pragma unroll
    for (int mf = 0; mf < 4; ++mf) {
      int r = mf * 16 + (lane & 15);
      int g = ks * 4 + (lane >> 4);
      int o = r * 256 + (g ^ (r & 7)) * 8;
      ah[mf] = *(const bf16x8*)&ZL[o];
    }
#pragma unroll
    for (int nf = 0; nf < 2; ++nf) {
      int c = wid * 32 + nf * 16 + (lane & 15);
      size_t o = (size_t)c * 256 + ks * 32 + (lane >> 4) * 8;
      bh[nf] = *(const bf16x8*)&Bh[o];
      bl[nf] = *(const bf16x8*)&Bl[o];
    }
#pragma unroll
    for (int mf = 0; mf < 4; ++mf)
#pragma unroll
      for (int nf = 0; nf < 2; ++nf) {
        acc[mf][nf] = __builtin_amdgcn_mfma_f32_16x16x32_bf16(
            ah[mf], bh[nf], acc[mf][nf], 0, 0, 0);
        acc[mf][nf] = __builtin_amdgcn_mfma_f32_16x16x32_bf16(
            ah[mf], bl[nf], acc[mf][nf], 0, 0, 0);
      }
  }

#pragma unroll
  for (int mf = 0; mf < 4; ++mf) {
    int r0 = row0 + mf * 16 + (lane >> 4) * 4;
#pragma unroll
    for (int nf = 0; nf < 2; ++nf) {
      int c = wid * 32 + nf * 16 + (lane & 15);
#pragma unroll
      for (int r = 0; r < 4; ++r)
        if (r0 + r < M) Cbf[(size_t)(r0 + r) * F + c] = f2bf(acc[mf][nf][r]);
    }
  }
}

extern "C" void kernel_launch(void* const* d_in, const int* in_sizes, int n_in,
                              void* d_out, int out_size, void* d_ws, size_t ws_size,
                              hipStream_t stream) {
  const float* x = (const float*)d_in[0];
  const int* ei = (const int*)d_in[1];
  const float* W1 = (const float*)d_in[2];
  const float* b1 = (const float*)d_in[3];
  const float* W2 = (const float*)d_in[4];
  const float* b2 = (const float*)d_in[5];
  float* out = (float*)d_out;

  int N = in_sizes[0] / F;  // 50000
  int E = in_sizes[1] / 2;  // 800000
  const int* src = ei;
  const int* dst = ei + E;

  // workspace layout (byte-based, 256B aligned chunks)
  char* ws = (char*)d_ws;
  size_t off = 0;
  auto allocB = [&](size_t bytes) {
    void* p = ws + off;
    off += ((bytes + 255) & ~(size_t)255);
    return p;
  };
  unsigned* deg = (unsigned*)allocB((size_t)N * 4);  // histogram, then cursor
  float* dinv = (float*)allocB((size_t)N * 4);
  int* rowptr = (int*)allocB(((size_t)N + 1) * 4);
  unsigned* bsum = (unsigned*)allocB(1024);
  int* esrc = (int*)allocB((size_t)E * 4);
  float* ew = (float*)allocB((size_t)E * 4);
  unsigned short* xb = (unsigned short*)allocB((size_t)N * F * 2);  // x bf16 table
  // +64 row padding so tail-block LDS staging reads stay in-bounds
  unsigned short* aggh = (unsigned short*)allocB((size_t)(N + 64) * F * 2);
  unsigned short* aggl = (unsigned short*)allocB((size_t)(N + 64) * F * 2);
  unsigned short* z1h = (unsigned short*)allocB((size_t)(N + 64) * HID * 2);
  unsigned short* w1th = (unsigned short*)allocB((size_t)F * HID * 2);
  unsigned short* w1tl = (unsigned short*)allocB((size_t)F * HID * 2);
  unsigned short* w2th = (unsigned short*)allocB((size_t)HID * F * 2);
  unsigned short* w2tl = (unsigned short*)allocB((size_t)HID * F * 2);
  // h2 bf16 (12.8MB) reuses the aggh plane (dead after GEMM1)
  unsigned short* h2b = aggh;

  int nbN = (N + 255) / 256;
  int nbE = (E + 255) / 256;
  int nbW = (F * HID + 255) / 256;
  int nbX = (N * F / 4 + 255) / 256;

  k_wsplit<<<nbW, 256, 0, stream>>>(W1, w1th, w1tl, F, HID);  // [256][128]
  k_wsplit<<<nbW, 256, 0, stream>>>(W2, w2th, w2tl, HID, F);  // [128][256]
  k_tobf<<<nbX, 256, 0, stream>>>(x, xb, N * F / 4);

  k_zero_deg<<<nbN, 256, 0, stream>>>(deg, N);
  k_deg_hist<<<nbE, 256, 0, stream>>>(dst, deg, E);
  k_dinv<<<nbN, 256, 0, stream>>>(deg, dinv, N);
  k_scan1<<<nbN, 256, 0, stream>>>(deg, rowptr, bsum, N);
  k_scan2<<<1, 256, 0, stream>>>(bsum, rowptr, nbN, N);
  k_scan3<<<nbN, 256, 0, stream>>>(bsum, rowptr, deg, N);
  k_scatter<<<nbE, 256, 0, stream>>>(src, dst, rowptr, deg, dinv, esrc, ew, E);

  int nbAgg = (N + 3) / 4;
  int mb = (N + 63) / 64;

  // layer 1: agg(hi/lo) = A x  (bf16 gather) ; z1(bf16) = relu(agg @ W1 + b1)
  k_agg_bf<<<nbAgg, 256, 0, stream>>>(rowptr, esrc, ew, dinv, x, xb, aggh, aggl, N);
  k_gemm1<<<mb, 256, 0, stream>>>(aggh, aggl, w1th, w1tl, b1, z1h, N);

  // layer 2: h2(bf16) = z1 @ W2 ; out = b2 + A h2  (bf16 gather)
  k_gemm2<<<mb, 256, 0, stream>>>(z1h, w2th, w2tl, h2b, N);
  k_agg_out<<<nbAgg, 256, 0, stream>>>(rowptr, esrc, ew, dinv, h2b, b2, out, N);
}